// Round 7
// baseline (578.940 us; speedup 1.0000x reference)
//
#include <hip/hip_runtime.h>
#include <math.h>

#define SEQ 1024
#define BATCH 4
#define DMODEL 512
#define NHEAD 8
#define DK 64
#define DFF 2048
#define U_TOP 34
#define ROWS (BATCH * SEQ)

typedef unsigned short ushort_t;
typedef __attribute__((ext_vector_type(8))) short short8;
typedef __attribute__((ext_vector_type(4))) float float4v;

__device__ inline ushort_t f2bf(float f) {
  unsigned u = __float_as_uint(f);
  unsigned r = u + 0x7fffu + ((u >> 16) & 1u);
  return (ushort_t)(r >> 16);
}
__device__ inline float bf2f(ushort_t u) {
  return __uint_as_float((unsigned)u << 16);
}
// ordered-uint key -> float (inverse of f -> sign?~u:u|0x80000000)
__device__ inline float keyinv(unsigned cand) {
  unsigned fb = (cand & 0x80000000u) ? (cand ^ 0x80000000u) : ~cand;
  return __uint_as_float(fb);
}

__device__ inline void glds16(const void* g, void* l) {
  __builtin_amdgcn_global_load_lds(
      (const __attribute__((address_space(1))) unsigned int*)g,
      (__attribute__((address_space(3))) unsigned int*)l, 16, 0, 0);
}

// ---------------------------------------------------------------------------
// bf16 MFMA GEMM, m97 structure: 128x128 tile, BK=32, 256 thr = 2x2 waves,
// 4x4 16x16x32 MFMAs per wave, 16 KB LDS. C = A @ Bt^T + bias, bf16 out.
// SPLIT=1 (QKV): Bt has 1536 rows (Wq|Wk|Wv); output col z=bn>>9 routes to
// Cout + z*zCstride with row stride 512 and bias {b0,b1,b2}[z].
// ---------------------------------------------------------------------------
template <int RELU, int SPLIT>
__global__ __launch_bounds__(256) void gemm128(
    const ushort_t* __restrict__ A, const short* __restrict__ Bt,
    const float* __restrict__ b0, const float* __restrict__ b1,
    const float* __restrict__ b2, ushort_t* __restrict__ Cout,
    int K, int N, int zCstride) {
  __shared__ short As[128 * 32];
  __shared__ short Bs[128 * 32];

  const int tid = threadIdx.x;
  const int lane = tid & 63, w = tid >> 6;
  const int wm = w >> 1, wn = w & 1;
  const int quad = lane >> 4, r16 = lane & 15;
  const int bm = blockIdx.y * 128, bn = blockIdx.x * 128;

  const int srow = lane >> 2, skseg = lane & 3;
  const ushort_t* Ag0 = A + (size_t)(bm + w * 16 + srow) * K + skseg * 8;
  const ushort_t* Ag1 = Ag0 + (size_t)64 * K;
  const short* Bg0 = Bt + (size_t)(bn + w * 16 + srow) * K + skseg * 8;
  const short* Bg1 = Bg0 + (size_t)64 * K;
  short* lA0 = As + (w * 16) * 32;
  short* lA1 = As + (64 + w * 16) * 32;
  short* lB0 = Bs + (w * 16) * 32;
  short* lB1 = Bs + (64 + w * 16) * 32;

  float4v acc[4][4];
#pragma unroll
  for (int m = 0; m < 4; ++m)
#pragma unroll
    for (int n = 0; n < 4; ++n) acc[m][n] = (float4v){0.f, 0.f, 0.f, 0.f};

  for (int k0 = 0; k0 < K; k0 += 32) {
    __syncthreads();
    glds16(Ag0 + k0, lA0);
    glds16(Ag1 + k0, lA1);
    glds16(Bg0 + k0, lB0);
    glds16(Bg1 + k0, lB1);
    __syncthreads();

    short8 af[4], bfr[4];
#pragma unroll
    for (int m = 0; m < 4; ++m)
      af[m] = *(const short8*)&As[(wm * 64 + m * 16 + r16) * 32 + quad * 8];
#pragma unroll
    for (int n = 0; n < 4; ++n)
      bfr[n] = *(const short8*)&Bs[(wn * 64 + n * 16 + r16) * 32 + quad * 8];
#pragma unroll
    for (int m = 0; m < 4; ++m)
#pragma unroll
      for (int n = 0; n < 4; ++n)
        acc[m][n] = __builtin_amdgcn_mfma_f32_16x16x32_bf16(af[m], bfr[n],
                                                            acc[m][n], 0, 0, 0);
  }

  const int z = SPLIT ? (bn >> 9) : 0;
  const float* bias = (z == 0) ? b0 : (z == 1 ? b1 : b2);
  const int cbase = SPLIT ? (bn & 511) : bn;
  const int strideN = SPLIT ? 512 : N;
  ushort_t* C = Cout + (SPLIT ? (size_t)z * zCstride : (size_t)0);

  float bias_n[4];
#pragma unroll
  for (int n = 0; n < 4; ++n)
    bias_n[n] = bias[cbase + wn * 64 + n * 16 + r16];

#pragma unroll
  for (int m = 0; m < 4; ++m) {
#pragma unroll
    for (int n = 0; n < 4; ++n) {
      int col = cbase + wn * 64 + n * 16 + r16;
#pragma unroll
      for (int reg = 0; reg < 4; ++reg) {
        int row = bm + wm * 64 + m * 16 + quad * 4 + reg;
        float v = acc[m][n][reg] + bias_n[n];
        if (RELU) v = fmaxf(v, 0.f);
        C[(size_t)row * strideN + col] = f2bf(v);
      }
    }
  }
}

// ---------------------------------------------------------------------------
// bf16 MFMA GEMM, tile 64x64, BK=32, 256 threads = 2x2 waves, 12 KB LDS.
// C = A[M,K] @ Bt[N,K]^T + bias (+ optional residual add from bf16 Cadd).
// EPI 0: none. EPI 2: v = v*sqrt(512) + positional encoding (embed).
// ---------------------------------------------------------------------------
template <int RELU, int OUTBF16, int EPI, int ADDC>
__global__ __launch_bounds__(256) void gemm64(
    const ushort_t* __restrict__ A, const short* __restrict__ Bt,
    const float* __restrict__ bias, void* __restrict__ Cout,
    const ushort_t* __restrict__ Cadd, int K, int N) {
  __shared__ short As[64 * 32];  // 4 KB
  __shared__ short Bs[64 * 32];  // 4 KB

  const int tid = threadIdx.x;
  const int lane = tid & 63, w = tid >> 6;
  const int wm = w >> 1, wn = w & 1;
  const int quad = lane >> 4, r16 = lane & 15;
  const int bm = blockIdx.y * 64, bn = blockIdx.x * 64;

  const int srow = tid >> 2, skseg = tid & 3;
  const ushort_t* Ag = A + (size_t)(bm + srow) * K + skseg * 8;
  const short* Bg = Bt + (size_t)(bn + srow) * K + skseg * 8;
  short* lA = As + w * 512;
  short* lB = Bs + w * 512;

  float4v acc[2][2];
#pragma unroll
  for (int m = 0; m < 2; ++m)
#pragma unroll
    for (int n = 0; n < 2; ++n) acc[m][n] = (float4v){0.f, 0.f, 0.f, 0.f};

  for (int k0 = 0; k0 < K; k0 += 32) {
    __syncthreads();
    glds16(Ag + k0, lA);
    glds16(Bg + k0, lB);
    __syncthreads();

    short8 af[2], bfr[2];
#pragma unroll
    for (int m = 0; m < 2; ++m)
      af[m] = *(const short8*)&As[(wm * 32 + m * 16 + r16) * 32 + quad * 8];
#pragma unroll
    for (int n = 0; n < 2; ++n)
      bfr[n] = *(const short8*)&Bs[(wn * 32 + n * 16 + r16) * 32 + quad * 8];
#pragma unroll
    for (int m = 0; m < 2; ++m)
#pragma unroll
      for (int n = 0; n < 2; ++n)
        acc[m][n] = __builtin_amdgcn_mfma_f32_16x16x32_bf16(af[m], bfr[n],
                                                            acc[m][n], 0, 0, 0);
  }

  const float pe_c = (float)(-9.210340371976184 / 512.0);
  const float sqrtd = 22.62741699796952f;

  float bias_n[2];
#pragma unroll
  for (int n = 0; n < 2; ++n) bias_n[n] = bias[bn + wn * 32 + n * 16 + r16];

#pragma unroll
  for (int m = 0; m < 2; ++m) {
#pragma unroll
    for (int n = 0; n < 2; ++n) {
      int col = bn + wn * 32 + n * 16 + r16;
#pragma unroll
      for (int reg = 0; reg < 4; ++reg) {
        int row = bm + wm * 32 + m * 16 + quad * 4 + reg;
        float v = acc[m][n][reg] + bias_n[n];
        if (RELU) v = fmaxf(v, 0.f);
        if (EPI == 2) {
          int pos = row & (SEQ - 1);
          float e = __expf((float)(col & ~1) * pe_c);
          float arg = (float)pos * e;
          v = v * sqrtd + ((col & 1) ? __cosf(arg) : __sinf(arg));
        }
        if (ADDC) v += bf2f(Cadd[(size_t)row * N + col]);
        if (OUTBF16) {
          ((ushort_t*)Cout)[(size_t)row * N + col] = f2bf(v);
        } else {
          ((float*)Cout)[(size_t)row * N + col] = v;
        }
      }
    }
  }
}

// ---------------------------------------------------------------------------
// All weights (3 layers + emb + dec): W[K][N] f32 -> Wt[N][K] bf16, 1 launch.
// ---------------------------------------------------------------------------
__global__ __launch_bounds__(256) void convert_all(
    const float* __restrict__ Wq, const float* __restrict__ Wk,
    const float* __restrict__ Wv, const float* __restrict__ Wo,
    const float* __restrict__ W1, const float* __restrict__ W2,
    const float* __restrict__ W_emb, const float* __restrict__ W_dec,
    short* __restrict__ wt) {
  __shared__ float t[32][33];
  int id = blockIdx.x;
  const float* src;
  short* dst;
  int K, N, tk, tn;
  if (id < 9216) {
    int lay = id / 3072, r = id % 3072;
    short* wl = wt + (size_t)lay * 3145728;
    const size_t wsz = 512 * 512;
    if (r < 1024) {
      int wi = r >> 8, tile = r & 255;
      const float* base = (wi == 0) ? Wq : (wi == 1) ? Wk : (wi == 2) ? Wv : Wo;
      src = base + lay * wsz;
      dst = wl + wi * 262144;
      K = 512; N = 512; tk = tile >> 4; tn = tile & 15;
    } else if (r < 2048) {
      int tile = r - 1024;
      src = W1 + (size_t)lay * 512 * 2048;
      dst = wl + 1048576;
      K = 512; N = 2048; tk = tile >> 6; tn = tile & 63;
    } else {
      int tile = r - 2048;
      src = W2 + (size_t)lay * 2048 * 512;
      dst = wl + 2097152;
      K = 2048; N = 512; tk = tile >> 4; tn = tile & 15;
    }
  } else {
    int r = id - 9216;
    if (r < 64) {
      src = W_emb; dst = wt + 9437184; K = 128; N = 512; tk = r >> 4; tn = r & 15;
    } else {
      r -= 64;
      src = W_dec; dst = wt + 9502720; K = 512; N = 64; tk = r >> 1; tn = r & 1;
    }
  }
  const int k0 = tk * 32, n0 = tn * 32;
  const int tx = threadIdx.x, ty = threadIdx.y;
#pragma unroll
  for (int i = 0; i < 4; ++i) {
    int r = ty + i * 8;
    t[r][tx] = src[(size_t)(k0 + r) * N + n0 + tx];
  }
  __syncthreads();
#pragma unroll
  for (int i = 0; i < 4; ++i) {
    int r = ty + i * 8;
    dst[(size_t)(n0 + r) * K + k0 + tx] = (short)f2bf(t[tx][r]);
  }
}

__global__ __launch_bounds__(256) void f32_to_bf16_kernel(
    const float* __restrict__ src, ushort_t* __restrict__ dst) {
  int i = blockIdx.x * blockDim.x + threadIdx.x;
  float4 v = ((const float4*)src)[i];
  ushort4 o;
  o.x = f2bf(v.x); o.y = f2bf(v.y); o.z = f2bf(v.z); o.w = f2bf(v.w);
  ((ushort4*)dst)[i] = o;
}

// ---------------------------------------------------------------------------
// LayerNorm on pre-summed bf16 input: hb[row] = LN(t1b[row]) * g + b.
// ---------------------------------------------------------------------------
__global__ __launch_bounds__(256) void ln_kernel(
    const ushort_t* __restrict__ t1b, const float* __restrict__ g,
    const float* __restrict__ bb, ushort_t* __restrict__ hb) {
  const int row = blockIdx.x * 4 + (threadIdx.x >> 6);
  const int lane = threadIdx.x & 63;
  const size_t base = (size_t)row * DMODEL + lane * 8;
  uint4 raw = *(const uint4*)(t1b + base);
  unsigned rr[4] = {raw.x, raw.y, raw.z, raw.w};
  float v[8];
#pragma unroll
  for (int k = 0; k < 4; ++k) {
    v[2 * k] = bf2f((ushort_t)(rr[k] & 0xffff));
    v[2 * k + 1] = bf2f((ushort_t)(rr[k] >> 16));
  }
  float sum = 0.f, sq = 0.f;
#pragma unroll
  for (int k = 0; k < 8; ++k) { sum += v[k]; sq += v[k] * v[k]; }
#pragma unroll
  for (int off = 32; off; off >>= 1) {
    sum += __shfl_xor(sum, off);
    sq += __shfl_xor(sq, off);
  }
  float mean = sum * (1.f / 512.f);
  float var = fmaxf(sq * (1.f / 512.f) - mean * mean, 0.f);
  float rstd = 1.f / sqrtf(var + 1e-5f);
  float4 g0 = *(const float4*)(g + lane * 8);
  float4 g1 = *(const float4*)(g + lane * 8 + 4);
  float4 c0 = *(const float4*)(bb + lane * 8);
  float4 c1 = *(const float4*)(bb + lane * 8 + 4);
  float gg[8] = {g0.x, g0.y, g0.z, g0.w, g1.x, g1.y, g1.z, g1.w};
  float cc[8] = {c0.x, c0.y, c0.z, c0.w, c1.x, c1.y, c1.z, c1.w};
  uint4 out;
  unsigned* op = (unsigned*)&out;
#pragma unroll
  for (int k = 0; k < 4; ++k) {
    float y0 = (v[2 * k] - mean) * rstd * gg[2 * k] + cc[2 * k];
    float y1 = (v[2 * k + 1] - mean) * rstd * gg[2 * k + 1] + cc[2 * k + 1];
    op[k] = (unsigned)f2bf(y0) | ((unsigned)f2bf(y1) << 16);
  }
  *(uint4*)(hb + base) = out;
}

// ---------------------------------------------------------------------------
// ProbSparse attention v6. Same as v5 but the standalone candidate-count
// pass is merged into the optimistic compaction (one 16-ballot pass total in
// the common path; stage-A fallback only if >64 candidates).
// ---------------------------------------------------------------------------
#define SSTR 1028

__global__ __launch_bounds__(1024, 8) void attn_kernel(
    const ushort_t* __restrict__ Qb, const ushort_t* __restrict__ Kb,
    const ushort_t* __restrict__ Vb, ushort_t* __restrict__ Ob) {
  __shared__ float s[16 * SSTR];
  __shared__ int jlist[16][64];
  __shared__ float wlist[16][64];

  const int tid = threadIdx.x;
  const int q0 = blockIdx.x * 16;
  const int h = blockIdx.y;
  const int b = blockIdx.z;
  const int w = tid >> 6;
  const int lane = tid & 63;
  const int quad = lane >> 4, r16 = lane & 15;

  // ---- Phase 1: MFMA scores ----
  {
    const int j0 = w * 64;
    const ushort_t* qrow =
        Qb + (size_t)(b * SEQ + q0 + r16) * DMODEL + h * DK + quad * 8;
    short8 aq0 = *(const short8*)qrow;
    short8 aq1 = *(const short8*)(qrow + 32);

    float4v acc[4];
#pragma unroll
    for (int nt = 0; nt < 4; ++nt) {
      const ushort_t* krow =
          Kb + (size_t)(b * SEQ + j0 + nt * 16 + r16) * DMODEL + h * DK +
          quad * 8;
      short8 bk0 = *(const short8*)krow;
      short8 bk1 = *(const short8*)(krow + 32);
      float4v a = (float4v){0.f, 0.f, 0.f, 0.f};
      a = __builtin_amdgcn_mfma_f32_16x16x32_bf16(aq0, bk0, a, 0, 0, 0);
      a = __builtin_amdgcn_mfma_f32_16x16x32_bf16(aq1, bk1, a, 0, 0, 0);
      acc[nt] = a;
    }
#pragma unroll
    for (int nt = 0; nt < 4; ++nt)
#pragma unroll
      for (int reg = 0; reg < 4; ++reg)
        s[(quad * 4 + reg) * SSTR + j0 + nt * 16 + r16] =
            acc[nt][reg] * 0.125f;
  }
  __syncthreads();

  // ---- Phase 2 ----
  {
    float v[16];
    float lmax = -1e30f;
#pragma unroll
    for (int i = 0; i < 16; ++i) {
      float f = s[w * SSTR + lane + 64 * i];
      v[i] = f;
      lmax = fmaxf(lmax, f);
    }
    float mx = lmax;
#pragma unroll
    for (int off = 32; off; off >>= 1) mx = fmaxf(mx, __shfl_xor(mx, off));

    // T-prefilter: exact 34th-largest of lane maxima (1 cmp/bit)
    unsigned ansT = 0u;
    {
      bool ex = false;
      for (int bit = 31; bit >= 0 && !ex; --bit) {
        unsigned cand = ansT | (1u << bit);
        float fc = keyinv(cand);
        int c = (int)__popcll(__ballot(lmax >= fc));
        if (c >= U_TOP) { ansT = cand; ex = (c == U_TOP); }
      }
    }
    const float fT = keyinv(ansT);

    const unsigned long long lmask_lt = (1ull << lane) - 1ull;
    float* tmpv = &wlist[w][0];
    int* tmpj = &jlist[w][0];

    // optimistic compaction at fT (also counts)
    int basec = 0;
#pragma unroll
    for (int i = 0; i < 16; ++i) {
      bool gk = v[i] >= fT;
      unsigned long long mask = __ballot(gk);
      if (gk) {
        int p = basec + (int)__popcll(mask & lmask_lt);
        if (p < 64) { tmpv[p] = v[i]; tmpj[p] = lane + 64 * i; }
      }
      basec += (int)__popcll(mask);
    }
    int ncand = basec;
    if (basec > 64) {
      // fallback: classic stage A (rare), recompact at tighter threshold
      unsigned ans = ansT;
      int cge = basec, bit = 31;
      bool ex = false;
      while (bit >= 0 && cge > 64 && !ex) {
        unsigned cand = ans | (1u << bit);
        float fc = keyinv(cand);
        int c = 0;
#pragma unroll
        for (int i = 0; i < 16; ++i) c += (int)__popcll(__ballot(v[i] >= fc));
        if (c >= U_TOP) { ans = cand; cge = c; ex = (c == U_TOP); }
        --bit;
      }
      float fa = keyinv(ans);
      int b2 = 0;
#pragma unroll
      for (int i = 0; i < 16; ++i) {
        bool gk = v[i] >= fa;
        unsigned long long mask = __ballot(gk);
        if (gk) {
          int p = b2 + (int)__popcll(mask & lmask_lt);
          if (p < 64) { tmpv[p] = v[i]; tmpj[p] = lane + 64 * i; }
        }
        b2 += (int)__popcll(mask);
      }
      ncand = b2 > 64 ? 64 : b2;
    }

    // one candidate per lane
    float cf = (lane < ncand) ? tmpv[lane] : -3.4e38f;
    int cj = (lane < ncand) ? tmpj[lane] : 0;

    // stage B: exact 34th-largest over candidates, 1 cmp/bit
    unsigned ansB = 0u;
    {
      bool ex = false;
      for (int bit = 31; bit >= 0 && !ex; --bit) {
        unsigned cand = ansB | (1u << bit);
        float fc = keyinv(cand);
        int c = (int)__popcll(__ballot(cf >= fc));
        if (c >= U_TOP) { ansB = cand; ex = (c == U_TOP); }
      }
    }
    const float thr = keyinv(ansB);

    // keep set, weights, final compaction
    bool keep = cf >= thr;
    unsigned long long kmask = __ballot(keep);
    int n = (int)__popcll(kmask);
    float e = keep ? __expf(cf - mx) : 0.f;
    float zsum = e;
#pragma unroll
    for (int off = 32; off; off >>= 1) zsum += __shfl_xor(zsum, off);
    int pos = (int)__popcll(kmask & lmask_lt);
    if (keep) { jlist[w][pos] = cj; wlist[w][pos] = e; }

    // sparse PV, unroll x4
    const ushort_t* vbase = Vb + (size_t)b * SEQ * DMODEL + h * DK;
    float o = 0.f;
    int i = 0;
    for (; i + 4 <= n; i += 4) {
      int j0 = jlist[w][i], j1 = jlist[w][i + 1];
      int j2 = jlist[w][i + 2], j3 = jlist[w][i + 3];
      float w0 = wlist[w][i], w1 = wlist[w][i + 1];
      float w2 = wlist[w][i + 2], w3 = wlist[w][i + 3];
      float p0 = bf2f(vbase[(size_t)j0 * DMODEL + lane]);
      float p1 = bf2f(vbase[(size_t)j1 * DMODEL + lane]);
      float p2 = bf2f(vbase[(size_t)j2 * DMODEL + lane]);
      float p3 = bf2f(vbase[(size_t)j3 * DMODEL + lane]);
      o += w0 * p0 + w1 * p1 + w2 * p2 + w3 * p3;
    }
    for (; i < n; ++i)
      o += wlist[w][i] * bf2f(vbase[(size_t)jlist[w][i] * DMODEL + lane]);
    o /= zsum;
    Ob[(size_t)(b * SEQ + q0 + w) * DMODEL + h * DK + lane] = f2bf(o);
  }
}

// ---------------------------------------------------------------------------
// Orchestration.  ws layout (MiB): ffh/qkv [0,16) | ao [16,20) (xb aliases
// [16,17) pre-loop) | t1b [20,24) | hb [24,28) | wt [28, 46.2).
// ---------------------------------------------------------------------------
extern "C" void kernel_launch(void* const* d_in, const int* in_sizes, int n_in,
                              void* d_out, int out_size, void* d_ws,
                              size_t ws_size, hipStream_t stream) {
  const float* x = (const float*)d_in[0];
  const float* W_emb = (const float*)d_in[1];
  const float* b_emb = (const float*)d_in[2];
  const float* Wq = (const float*)d_in[3];
  const float* bq = (const float*)d_in[4];
  const float* Wk = (const float*)d_in[5];
  const float* bk = (const float*)d_in[6];
  const float* Wv = (const float*)d_in[7];
  const float* bv = (const float*)d_in[8];
  const float* Wo = (const float*)d_in[9];
  const float* bo = (const float*)d_in[10];
  const float* ln1_g = (const float*)d_in[11];
  const float* ln1_b = (const float*)d_in[12];
  const float* W1 = (const float*)d_in[13];
  const float* b1 = (const float*)d_in[14];
  const float* W2 = (const float*)d_in[15];
  const float* b2 = (const float*)d_in[16];
  const float* ln2_g = (const float*)d_in[17];
  const float* ln2_b = (const float*)d_in[18];
  const float* W_dec = (const float*)d_in[19];
  const float* b_dec = (const float*)d_in[20];

  char* wsb = (char*)d_ws;
  ushort_t* qkv = (ushort_t*)wsb;
  ushort_t* ffh = (ushort_t*)wsb;
  ushort_t* ao = (ushort_t*)(wsb + ((size_t)16 << 20));
  ushort_t* xb = (ushort_t*)(wsb + ((size_t)16 << 20));
  ushort_t* t1b = (ushort_t*)(wsb + ((size_t)20 << 20));
  ushort_t* hb = (ushort_t*)(wsb + ((size_t)24 << 20));
  short* wt = (short*)(wsb + ((size_t)28 << 20));
  short* wembT = wt + 9437184;
  short* wdecT = wt + 9502720;

  f32_to_bf16_kernel<<<dim3(512), 256, 0, stream>>>(x, xb);
  convert_all<<<dim3(9312), dim3(32, 8), 0, stream>>>(Wq, Wk, Wv, Wo, W1, W2,
                                                      W_emb, W_dec, wt);
  // embed: hb = bf16((xb @ W_emb + b_emb)*sqrt(512) + PE)
  gemm64<0, 1, 2, 0><<<dim3(8, 64), 256, 0, stream>>>(
      xb, wembT, b_emb, (void*)hb, nullptr, 128, 512);

  for (int i = 0; i < 3; ++i) {
    short* wtL = wt + (size_t)i * 3145728;

    // QKV: one N=1536 GEMM on the 128x128 tile, z-split epilogue
    gemm128<0, 1><<<dim3(12, 32), 256, 0, stream>>>(
        hb, wtL, bq + i * DMODEL, bk + i * DMODEL, bv + i * DMODEL, qkv, 512,
        512, 2097152);

    attn_kernel<<<dim3(SEQ / 16, NHEAD, BATCH), dim3(1024), 0, stream>>>(
        qkv, qkv + 2097152, qkv + 4194304, ao);

    // t1b = ao @ Wo + bo + hb   (residual fused)
    gemm64<0, 1, 0, 1><<<dim3(8, 64), 256, 0, stream>>>(
        ao, wtL + 786432, bo + i * DMODEL, (void*)t1b, hb, 512, 512);
    ln_kernel<<<dim3(ROWS / 4), 256, 0, stream>>>(
        t1b, ln1_g + i * DMODEL, ln1_b + i * DMODEL, hb);

    // FFN1 on the 128x128 tile (N=2048)
    gemm128<1, 0><<<dim3(16, 32), 256, 0, stream>>>(
        hb, wtL + 1048576, b1 + i * DFF, nullptr, nullptr, ffh, 512, 2048, 0);
    // t1b = ffh @ W2 + b2 + hb  (residual fused)
    gemm64<0, 1, 0, 1><<<dim3(8, 64), 256, 0, stream>>>(
        ffh, wtL + 2097152, b2 + i * DMODEL, (void*)t1b, hb, 2048, 512);
    ln_kernel<<<dim3(ROWS / 4), 256, 0, stream>>>(
        t1b, ln2_g + i * DMODEL, ln2_b + i * DMODEL, hb);
  }

  gemm64<0, 0, 0, 0><<<dim3(1, 64), 256, 0, stream>>>(
      hb, wdecT, b_dec, d_out, nullptr, 512, 64);
}

// Round 8
// 557.292 us; speedup vs baseline: 1.0388x; 1.0388x over previous
//
#include <hip/hip_runtime.h>
#include <math.h>

#define SEQ 1024
#define BATCH 4
#define DMODEL 512
#define NHEAD 8
#define DK 64
#define DFF 2048
#define U_TOP 34
#define ROWS (BATCH * SEQ)

typedef unsigned short ushort_t;
typedef __attribute__((ext_vector_type(8))) short short8;
typedef __attribute__((ext_vector_type(4))) float float4v;

__device__ inline ushort_t f2bf(float f) {
  unsigned u = __float_as_uint(f);
  unsigned r = u + 0x7fffu + ((u >> 16) & 1u);
  return (ushort_t)(r >> 16);
}
__device__ inline float bf2f(ushort_t u) {
  return __uint_as_float((unsigned)u << 16);
}
// ordered-uint key -> float (used only in the rare >64-candidate fallback)
__device__ inline float keyinv(unsigned cand) {
  unsigned fb = (cand & 0x80000000u) ? (cand ^ 0x80000000u) : ~cand;
  return __uint_as_float(fb);
}

__device__ inline void glds16(const void* g, void* l) {
  __builtin_amdgcn_global_load_lds(
      (const __attribute__((address_space(1))) unsigned int*)g,
      (__attribute__((address_space(3))) unsigned int*)l, 16, 0, 0);
}

// Descending bitonic sort of one value/lane across the 64-lane wave.
// After: lane 0 holds max, lane i holds (i+1)-th largest.
__device__ inline float bitonic64_desc(float sv, int lane) {
#pragma unroll
  for (int k = 2; k <= 64; k <<= 1) {
#pragma unroll
    for (int j = k >> 1; j > 0; j >>= 1) {
      float pv = __shfl_xor(sv, j);
      bool keepMin = (((lane & k) != 0) == ((lane & j) == 0));
      sv = keepMin ? fminf(sv, pv) : fmaxf(sv, pv);
    }
  }
  return sv;
}

// ---------------------------------------------------------------------------
// bf16 MFMA GEMM, m97 structure: 128x128 tile, BK=32, 256 thr = 2x2 waves.
// SPLIT=1 (QKV): Bt has 1536 rows (Wq|Wk|Wv); z=bn>>9 routes output/bias.
// ---------------------------------------------------------------------------
template <int RELU, int SPLIT>
__global__ __launch_bounds__(256) void gemm128(
    const ushort_t* __restrict__ A, const short* __restrict__ Bt,
    const float* __restrict__ b0, const float* __restrict__ b1,
    const float* __restrict__ b2, ushort_t* __restrict__ Cout,
    int K, int N, int zCstride) {
  __shared__ short As[128 * 32];
  __shared__ short Bs[128 * 32];

  const int tid = threadIdx.x;
  const int lane = tid & 63, w = tid >> 6;
  const int wm = w >> 1, wn = w & 1;
  const int quad = lane >> 4, r16 = lane & 15;
  const int bm = blockIdx.y * 128, bn = blockIdx.x * 128;

  const int srow = lane >> 2, skseg = lane & 3;
  const ushort_t* Ag0 = A + (size_t)(bm + w * 16 + srow) * K + skseg * 8;
  const ushort_t* Ag1 = Ag0 + (size_t)64 * K;
  const short* Bg0 = Bt + (size_t)(bn + w * 16 + srow) * K + skseg * 8;
  const short* Bg1 = Bg0 + (size_t)64 * K;
  short* lA0 = As + (w * 16) * 32;
  short* lA1 = As + (64 + w * 16) * 32;
  short* lB0 = Bs + (w * 16) * 32;
  short* lB1 = Bs + (64 + w * 16) * 32;

  float4v acc[4][4];
#pragma unroll
  for (int m = 0; m < 4; ++m)
#pragma unroll
    for (int n = 0; n < 4; ++n) acc[m][n] = (float4v){0.f, 0.f, 0.f, 0.f};

  for (int k0 = 0; k0 < K; k0 += 32) {
    __syncthreads();
    glds16(Ag0 + k0, lA0);
    glds16(Ag1 + k0, lA1);
    glds16(Bg0 + k0, lB0);
    glds16(Bg1 + k0, lB1);
    __syncthreads();

    short8 af[4], bfr[4];
#pragma unroll
    for (int m = 0; m < 4; ++m)
      af[m] = *(const short8*)&As[(wm * 64 + m * 16 + r16) * 32 + quad * 8];
#pragma unroll
    for (int n = 0; n < 4; ++n)
      bfr[n] = *(const short8*)&Bs[(wn * 64 + n * 16 + r16) * 32 + quad * 8];
#pragma unroll
    for (int m = 0; m < 4; ++m)
#pragma unroll
      for (int n = 0; n < 4; ++n)
        acc[m][n] = __builtin_amdgcn_mfma_f32_16x16x32_bf16(af[m], bfr[n],
                                                            acc[m][n], 0, 0, 0);
  }

  const int z = SPLIT ? (bn >> 9) : 0;
  const float* bias = (z == 0) ? b0 : (z == 1 ? b1 : b2);
  const int cbase = SPLIT ? (bn & 511) : bn;
  const int strideN = SPLIT ? 512 : N;
  ushort_t* C = Cout + (SPLIT ? (size_t)z * zCstride : (size_t)0);

  float bias_n[4];
#pragma unroll
  for (int n = 0; n < 4; ++n)
    bias_n[n] = bias[cbase + wn * 64 + n * 16 + r16];

#pragma unroll
  for (int m = 0; m < 4; ++m) {
#pragma unroll
    for (int n = 0; n < 4; ++n) {
      int col = cbase + wn * 64 + n * 16 + r16;
#pragma unroll
      for (int reg = 0; reg < 4; ++reg) {
        int row = bm + wm * 64 + m * 16 + quad * 4 + reg;
        float v = acc[m][n][reg] + bias_n[n];
        if (RELU) v = fmaxf(v, 0.f);
        C[(size_t)row * strideN + col] = f2bf(v);
      }
    }
  }
}

// ---------------------------------------------------------------------------
// bf16 MFMA GEMM, tile 64x64, BK=32, 256 threads = 2x2 waves, 12 KB LDS.
// EPI 0: none. EPI 2: v = v*sqrt(512) + positional encoding (embed).
// ---------------------------------------------------------------------------
template <int RELU, int OUTBF16, int EPI, int ADDC>
__global__ __launch_bounds__(256) void gemm64(
    const ushort_t* __restrict__ A, const short* __restrict__ Bt,
    const float* __restrict__ bias, void* __restrict__ Cout,
    const ushort_t* __restrict__ Cadd, int K, int N) {
  __shared__ short As[64 * 32];
  __shared__ short Bs[64 * 32];

  const int tid = threadIdx.x;
  const int lane = tid & 63, w = tid >> 6;
  const int wm = w >> 1, wn = w & 1;
  const int quad = lane >> 4, r16 = lane & 15;
  const int bm = blockIdx.y * 64, bn = blockIdx.x * 64;

  const int srow = tid >> 2, skseg = tid & 3;
  const ushort_t* Ag = A + (size_t)(bm + srow) * K + skseg * 8;
  const short* Bg = Bt + (size_t)(bn + srow) * K + skseg * 8;
  short* lA = As + w * 512;
  short* lB = Bs + w * 512;

  float4v acc[2][2];
#pragma unroll
  for (int m = 0; m < 2; ++m)
#pragma unroll
    for (int n = 0; n < 2; ++n) acc[m][n] = (float4v){0.f, 0.f, 0.f, 0.f};

  for (int k0 = 0; k0 < K; k0 += 32) {
    __syncthreads();
    glds16(Ag + k0, lA);
    glds16(Bg + k0, lB);
    __syncthreads();

    short8 af[2], bfr[2];
#pragma unroll
    for (int m = 0; m < 2; ++m)
      af[m] = *(const short8*)&As[(wm * 32 + m * 16 + r16) * 32 + quad * 8];
#pragma unroll
    for (int n = 0; n < 2; ++n)
      bfr[n] = *(const short8*)&Bs[(wn * 32 + n * 16 + r16) * 32 + quad * 8];
#pragma unroll
    for (int m = 0; m < 2; ++m)
#pragma unroll
      for (int n = 0; n < 2; ++n)
        acc[m][n] = __builtin_amdgcn_mfma_f32_16x16x32_bf16(af[m], bfr[n],
                                                            acc[m][n], 0, 0, 0);
  }

  const float pe_c = (float)(-9.210340371976184 / 512.0);
  const float sqrtd = 22.62741699796952f;

  float bias_n[2];
#pragma unroll
  for (int n = 0; n < 2; ++n) bias_n[n] = bias[bn + wn * 32 + n * 16 + r16];

#pragma unroll
  for (int m = 0; m < 2; ++m) {
#pragma unroll
    for (int n = 0; n < 2; ++n) {
      int col = bn + wn * 32 + n * 16 + r16;
#pragma unroll
      for (int reg = 0; reg < 4; ++reg) {
        int row = bm + wm * 32 + m * 16 + quad * 4 + reg;
        float v = acc[m][n][reg] + bias_n[n];
        if (RELU) v = fmaxf(v, 0.f);
        if (EPI == 2) {
          int pos = row & (SEQ - 1);
          float e = __expf((float)(col & ~1) * pe_c);
          float arg = (float)pos * e;
          v = v * sqrtd + ((col & 1) ? __cosf(arg) : __sinf(arg));
        }
        if (ADDC) v += bf2f(Cadd[(size_t)row * N + col]);
        if (OUTBF16) {
          ((ushort_t*)Cout)[(size_t)row * N + col] = f2bf(v);
        } else {
          ((float*)Cout)[(size_t)row * N + col] = v;
        }
      }
    }
  }
}

// ---------------------------------------------------------------------------
// All weights (3 layers + emb + dec): W[K][N] f32 -> Wt[N][K] bf16, 1 launch.
// ---------------------------------------------------------------------------
__global__ __launch_bounds__(256) void convert_all(
    const float* __restrict__ Wq, const float* __restrict__ Wk,
    const float* __restrict__ Wv, const float* __restrict__ Wo,
    const float* __restrict__ W1, const float* __restrict__ W2,
    const float* __restrict__ W_emb, const float* __restrict__ W_dec,
    short* __restrict__ wt) {
  __shared__ float t[32][33];
  int id = blockIdx.x;
  const float* src;
  short* dst;
  int K, N, tk, tn;
  if (id < 9216) {
    int lay = id / 3072, r = id % 3072;
    short* wl = wt + (size_t)lay * 3145728;
    const size_t wsz = 512 * 512;
    if (r < 1024) {
      int wi = r >> 8, tile = r & 255;
      const float* base = (wi == 0) ? Wq : (wi == 1) ? Wk : (wi == 2) ? Wv : Wo;
      src = base + lay * wsz;
      dst = wl + wi * 262144;
      K = 512; N = 512; tk = tile >> 4; tn = tile & 15;
    } else if (r < 2048) {
      int tile = r - 1024;
      src = W1 + (size_t)lay * 512 * 2048;
      dst = wl + 1048576;
      K = 512; N = 2048; tk = tile >> 6; tn = tile & 63;
    } else {
      int tile = r - 2048;
      src = W2 + (size_t)lay * 2048 * 512;
      dst = wl + 2097152;
      K = 2048; N = 512; tk = tile >> 4; tn = tile & 15;
    }
  } else {
    int r = id - 9216;
    if (r < 64) {
      src = W_emb; dst = wt + 9437184; K = 128; N = 512; tk = r >> 4; tn = r & 15;
    } else {
      r -= 64;
      src = W_dec; dst = wt + 9502720; K = 512; N = 64; tk = r >> 1; tn = r & 1;
    }
  }
  const int k0 = tk * 32, n0 = tn * 32;
  const int tx = threadIdx.x, ty = threadIdx.y;
#pragma unroll
  for (int i = 0; i < 4; ++i) {
    int r = ty + i * 8;
    t[r][tx] = src[(size_t)(k0 + r) * N + n0 + tx];
  }
  __syncthreads();
#pragma unroll
  for (int i = 0; i < 4; ++i) {
    int r = ty + i * 8;
    dst[(size_t)(n0 + r) * K + k0 + tx] = (short)f2bf(t[tx][r]);
  }
}

__global__ __launch_bounds__(256) void f32_to_bf16_kernel(
    const float* __restrict__ src, ushort_t* __restrict__ dst) {
  int i = blockIdx.x * blockDim.x + threadIdx.x;
  float4 v = ((const float4*)src)[i];
  ushort4 o;
  o.x = f2bf(v.x); o.y = f2bf(v.y); o.z = f2bf(v.z); o.w = f2bf(v.w);
  ((ushort4*)dst)[i] = o;
}

// ---------------------------------------------------------------------------
// LayerNorm on pre-summed bf16 input: hb[row] = LN(t1b[row]) * g + b.
// ---------------------------------------------------------------------------
__global__ __launch_bounds__(256) void ln_kernel(
    const ushort_t* __restrict__ t1b, const float* __restrict__ g,
    const float* __restrict__ bb, ushort_t* __restrict__ hb) {
  const int row = blockIdx.x * 4 + (threadIdx.x >> 6);
  const int lane = threadIdx.x & 63;
  const size_t base = (size_t)row * DMODEL + lane * 8;
  uint4 raw = *(const uint4*)(t1b + base);
  unsigned rr[4] = {raw.x, raw.y, raw.z, raw.w};
  float v[8];
#pragma unroll
  for (int k = 0; k < 4; ++k) {
    v[2 * k] = bf2f((ushort_t)(rr[k] & 0xffff));
    v[2 * k + 1] = bf2f((ushort_t)(rr[k] >> 16));
  }
  float sum = 0.f, sq = 0.f;
#pragma unroll
  for (int k = 0; k < 8; ++k) { sum += v[k]; sq += v[k] * v[k]; }
#pragma unroll
  for (int off = 32; off; off >>= 1) {
    sum += __shfl_xor(sum, off);
    sq += __shfl_xor(sq, off);
  }
  float mean = sum * (1.f / 512.f);
  float var = fmaxf(sq * (1.f / 512.f) - mean * mean, 0.f);
  float rstd = 1.f / sqrtf(var + 1e-5f);
  float4 g0 = *(const float4*)(g + lane * 8);
  float4 g1 = *(const float4*)(g + lane * 8 + 4);
  float4 c0 = *(const float4*)(bb + lane * 8);
  float4 c1 = *(const float4*)(bb + lane * 8 + 4);
  float gg[8] = {g0.x, g0.y, g0.z, g0.w, g1.x, g1.y, g1.z, g1.w};
  float cc[8] = {c0.x, c0.y, c0.z, c0.w, c1.x, c1.y, c1.z, c1.w};
  uint4 out;
  unsigned* op = (unsigned*)&out;
#pragma unroll
  for (int k = 0; k < 4; ++k) {
    float y0 = (v[2 * k] - mean) * rstd * gg[2 * k] + cc[2 * k];
    float y1 = (v[2 * k + 1] - mean) * rstd * gg[2 * k + 1] + cc[2 * k + 1];
    op[k] = (unsigned)f2bf(y0) | ((unsigned)f2bf(y1) << 16);
  }
  *(uint4*)(hb + base) = out;
}

// ---------------------------------------------------------------------------
// ProbSparse attention v7: bisections replaced with cross-lane bitonic sorts
// (no loop-carried scalar dependency chains).
//   sort1: 64 lane-maxima desc -> mx = lane0, fT = lane33 (34th-largest
//   lane-max <= global 34th: subset k-th largest <= full-set k-th largest).
//   compact candidates {v >= fT} (>=34 guaranteed; <=64 typical).
//   sort2 on a copy of the one-per-lane candidates -> thr = lane33 = exact
//   global 34th-largest. Fallback 16-ballot bisection only if >64 candidates.
// ---------------------------------------------------------------------------
#define SSTR 1028

__global__ __launch_bounds__(1024, 8) void attn_kernel(
    const ushort_t* __restrict__ Qb, const ushort_t* __restrict__ Kb,
    const ushort_t* __restrict__ Vb, ushort_t* __restrict__ Ob) {
  __shared__ float s[16 * SSTR];
  __shared__ int jlist[16][64];
  __shared__ float wlist[16][64];

  const int tid = threadIdx.x;
  const int q0 = blockIdx.x * 16;
  const int h = blockIdx.y;
  const int b = blockIdx.z;
  const int w = tid >> 6;
  const int lane = tid & 63;
  const int quad = lane >> 4, r16 = lane & 15;

  // ---- Phase 1: MFMA scores ----
  {
    const int j0 = w * 64;
    const ushort_t* qrow =
        Qb + (size_t)(b * SEQ + q0 + r16) * DMODEL + h * DK + quad * 8;
    short8 aq0 = *(const short8*)qrow;
    short8 aq1 = *(const short8*)(qrow + 32);

    float4v acc[4];
#pragma unroll
    for (int nt = 0; nt < 4; ++nt) {
      const ushort_t* krow =
          Kb + (size_t)(b * SEQ + j0 + nt * 16 + r16) * DMODEL + h * DK +
          quad * 8;
      short8 bk0 = *(const short8*)krow;
      short8 bk1 = *(const short8*)(krow + 32);
      float4v a = (float4v){0.f, 0.f, 0.f, 0.f};
      a = __builtin_amdgcn_mfma_f32_16x16x32_bf16(aq0, bk0, a, 0, 0, 0);
      a = __builtin_amdgcn_mfma_f32_16x16x32_bf16(aq1, bk1, a, 0, 0, 0);
      acc[nt] = a;
    }
#pragma unroll
    for (int nt = 0; nt < 4; ++nt)
#pragma unroll
      for (int reg = 0; reg < 4; ++reg)
        s[(quad * 4 + reg) * SSTR + j0 + nt * 16 + r16] =
            acc[nt][reg] * 0.125f;
  }
  __syncthreads();

  // ---- Phase 2 ----
  {
    float v[16];
    float lmax = -1e30f;
#pragma unroll
    for (int i = 0; i < 16; ++i) {
      float f = s[w * SSTR + lane + 64 * i];
      v[i] = f;
      lmax = fmaxf(lmax, f);
    }

    // sort1: lane maxima descending
    float srt = bitonic64_desc(lmax, lane);
    const float mx = __shfl(srt, 0);
    const float fT = __shfl(srt, 33);

    const unsigned long long lmask_lt = (1ull << lane) - 1ull;
    float* tmpv = &wlist[w][0];
    int* tmpj = &jlist[w][0];

    // optimistic compaction at fT (also counts)
    int basec = 0;
#pragma unroll
    for (int i = 0; i < 16; ++i) {
      bool gk = v[i] >= fT;
      unsigned long long mask = __ballot(gk);
      if (gk) {
        int p = basec + (int)__popcll(mask & lmask_lt);
        if (p < 64) { tmpv[p] = v[i]; tmpj[p] = lane + 64 * i; }
      }
      basec += (int)__popcll(mask);
    }
    int ncand = basec;
    if (basec > 64) {
      // fallback: ballot bisection (rare), recompact at tighter threshold
      unsigned ans = 0u;
      int cge = basec, bit = 31;
      bool ex = false;
      while (bit >= 0 && cge > 64 && !ex) {
        unsigned cand = ans | (1u << bit);
        float fc = keyinv(cand);
        int c = 0;
#pragma unroll
        for (int i = 0; i < 16; ++i) c += (int)__popcll(__ballot(v[i] >= fc));
        if (c >= U_TOP) { ans = cand; cge = c; ex = (c == U_TOP); }
        --bit;
      }
      float fa = keyinv(ans);
      int b2 = 0;
#pragma unroll
      for (int i = 0; i < 16; ++i) {
        bool gk = v[i] >= fa;
        unsigned long long mask = __ballot(gk);
        if (gk) {
          int p = b2 + (int)__popcll(mask & lmask_lt);
          if (p < 64) { tmpv[p] = v[i]; tmpj[p] = lane + 64 * i; }
        }
        b2 += (int)__popcll(mask);
      }
      ncand = b2 > 64 ? 64 : b2;
    }

    // one candidate per lane
    float cf = (lane < ncand) ? tmpv[lane] : -3.4e38f;
    int cj = (lane < ncand) ? tmpj[lane] : 0;

    // sort2: exact 34th-largest over candidates (ncand >= 34 guaranteed)
    float srt2 = bitonic64_desc(cf, lane);
    const float thr = __shfl(srt2, 33);

    // keep set, weights, final compaction
    bool keep = cf >= thr;
    unsigned long long kmask = __ballot(keep);
    int n = (int)__popcll(kmask);
    float e = keep ? __expf(cf - mx) : 0.f;
    float zsum = e;
#pragma unroll
    for (int off = 32; off; off >>= 1) zsum += __shfl_xor(zsum, off);
    int pos = (int)__popcll(kmask & lmask_lt);
    if (keep) { jlist[w][pos] = cj; wlist[w][pos] = e; }

    // sparse PV, unroll x4
    const ushort_t* vbase = Vb + (size_t)b * SEQ * DMODEL + h * DK;
    float o = 0.f;
    int i = 0;
    for (; i + 4 <= n; i += 4) {
      int j0 = jlist[w][i], j1 = jlist[w][i + 1];
      int j2 = jlist[w][i + 2], j3 = jlist[w][i + 3];
      float w0 = wlist[w][i], w1 = wlist[w][i + 1];
      float w2 = wlist[w][i + 2], w3 = wlist[w][i + 3];
      float p0 = bf2f(vbase[(size_t)j0 * DMODEL + lane]);
      float p1 = bf2f(vbase[(size_t)j1 * DMODEL + lane]);
      float p2 = bf2f(vbase[(size_t)j2 * DMODEL + lane]);
      float p3 = bf2f(vbase[(size_t)j3 * DMODEL + lane]);
      o += w0 * p0 + w1 * p1 + w2 * p2 + w3 * p3;
    }
    for (; i < n; ++i)
      o += wlist[w][i] * bf2f(vbase[(size_t)jlist[w][i] * DMODEL + lane]);
    o /= zsum;
    Ob[(size_t)(b * SEQ + q0 + w) * DMODEL + h * DK + lane] = f2bf(o);
  }
}

// ---------------------------------------------------------------------------
// Orchestration.  ws layout (MiB): ffh/qkv [0,16) | ao [16,20) (xb aliases
// [16,17) pre-loop) | t1b [20,24) | hb [24,28) | wt [28, 46.2).
// ---------------------------------------------------------------------------
extern "C" void kernel_launch(void* const* d_in, const int* in_sizes, int n_in,
                              void* d_out, int out_size, void* d_ws,
                              size_t ws_size, hipStream_t stream) {
  const float* x = (const float*)d_in[0];
  const float* W_emb = (const float*)d_in[1];
  const float* b_emb = (const float*)d_in[2];
  const float* Wq = (const float*)d_in[3];
  const float* bq = (const float*)d_in[4];
  const float* Wk = (const float*)d_in[5];
  const float* bk = (const float*)d_in[6];
  const float* Wv = (const float*)d_in[7];
  const float* bv = (const float*)d_in[8];
  const float* Wo = (const float*)d_in[9];
  const float* bo = (const float*)d_in[10];
  const float* ln1_g = (const float*)d_in[11];
  const float* ln1_b = (const float*)d_in[12];
  const float* W1 = (const float*)d_in[13];
  const float* b1 = (const float*)d_in[14];
  const float* W2 = (const float*)d_in[15];
  const float* b2 = (const float*)d_in[16];
  const float* ln2_g = (const float*)d_in[17];
  const float* ln2_b = (const float*)d_in[18];
  const float* W_dec = (const float*)d_in[19];
  const float* b_dec = (const float*)d_in[20];

  char* wsb = (char*)d_ws;
  ushort_t* qkv = (ushort_t*)wsb;
  ushort_t* ffh = (ushort_t*)wsb;
  ushort_t* ao = (ushort_t*)(wsb + ((size_t)16 << 20));
  ushort_t* xb = (ushort_t*)(wsb + ((size_t)16 << 20));
  ushort_t* t1b = (ushort_t*)(wsb + ((size_t)20 << 20));
  ushort_t* hb = (ushort_t*)(wsb + ((size_t)24 << 20));
  short* wt = (short*)(wsb + ((size_t)28 << 20));
  short* wembT = wt + 9437184;
  short* wdecT = wt + 9502720;

  f32_to_bf16_kernel<<<dim3(512), 256, 0, stream>>>(x, xb);
  convert_all<<<dim3(9312), dim3(32, 8), 0, stream>>>(Wq, Wk, Wv, Wo, W1, W2,
                                                      W_emb, W_dec, wt);
  // embed: hb = bf16((xb @ W_emb + b_emb)*sqrt(512) + PE)
  gemm64<0, 1, 2, 0><<<dim3(8, 64), 256, 0, stream>>>(
      xb, wembT, b_emb, (void*)hb, nullptr, 128, 512);

  for (int i = 0; i < 3; ++i) {
    short* wtL = wt + (size_t)i * 3145728;

    // QKV: one N=1536 GEMM on the 128x128 tile, z-split epilogue
    gemm128<0, 1><<<dim3(12, 32), 256, 0, stream>>>(
        hb, wtL, bq + i * DMODEL, bk + i * DMODEL, bv + i * DMODEL, qkv, 512,
        512, 2097152);

    attn_kernel<<<dim3(SEQ / 16, NHEAD, BATCH), dim3(1024), 0, stream>>>(
        qkv, qkv + 2097152, qkv + 4194304, ao);

    // t1b = ao @ Wo + bo + hb   (residual fused)
    gemm64<0, 1, 0, 1><<<dim3(8, 64), 256, 0, stream>>>(
        ao, wtL + 786432, bo + i * DMODEL, (void*)t1b, hb, 512, 512);
    ln_kernel<<<dim3(ROWS / 4), 256, 0, stream>>>(
        t1b, ln1_g + i * DMODEL, ln1_b + i * DMODEL, hb);

    // FFN1 on the 128x128 tile (N=2048)
    gemm128<1, 0><<<dim3(16, 32), 256, 0, stream>>>(
        hb, wtL + 1048576, b1 + i * DFF, nullptr, nullptr, ffh, 512, 2048, 0);
    // t1b = ffh @ W2 + b2 + hb  (residual fused)
    gemm64<0, 1, 0, 1><<<dim3(8, 64), 256, 0, stream>>>(
        ffh, wtL + 2097152, b2 + i * DMODEL, (void*)t1b, hb, 2048, 512);
    ln_kernel<<<dim3(ROWS / 4), 256, 0, stream>>>(
        t1b, ln2_g + i * DMODEL, ln2_b + i * DMODEL, hb);
  }

  gemm64<0, 0, 0, 0><<<dim3(1, 64), 256, 0, stream>>>(
      hb, wdecT, b_dec, d_out, nullptr, 512, 64);
}